// Round 1
// baseline (96.258 us; speedup 1.0000x reference)
//
#include <hip/hip_runtime.h>
#include <math.h>

#define NN 32
#define STRIDE3 96            // 3*NN floats per batch element
#define PI_F 3.14159265358979323846f

// d_ws layout (floats):
//   [0..32)     va2pi = 2*pi*5*sigmoid(v)
//   [32..64)    ba    = 2*sigmoid(b)
//   [64..96)    ca    = 10*sigmoid(c)
//   [128..1152) A row-major 32x32  (w_a * cos(phi_a), zero diag)
//   [1152..2176)B row-major 32x32  (w_a * sin(phi_a), zero diag)

__global__ void precompute_kernel(const float* __restrict__ v,
                                  const float* __restrict__ b,
                                  const float* __restrict__ c,
                                  const float* __restrict__ w,
                                  const float* __restrict__ phi,
                                  float* __restrict__ ws) {
    const int t = threadIdx.x;  // 0..1023, t = 32*i + j of the zero-diag matrix
    // _zero_diag mapping: flat index t -> 0 if t%33==0 (covers diagonal and t==1023),
    // else param[t/33][t%33 - 1]
    float A = 0.f, B = 0.f;
    const int rem = t % 33;
    if (rem != 0) {
        const int a = t / 33;
        const int col = rem - 1;
        const float wr = w[a * NN + col];
        const float pr = phi[a * NN + col];
        const float wa = 1.0f / (1.0f + __expf(-wr));            // W_MAX = 1
        const float pa = (2.0f * PI_F) / (1.0f + __expf(-pr));   // PHI_MAX = 2*pi
        float sp, cp;
        __sincosf(pa, &sp, &cp);
        A = wa * cp;
        B = wa * sp;
    }
    ws[128 + t] = A;
    ws[1152 + t] = B;
    if (t < NN) {
        ws[t] = 2.0f * PI_F * 5.0f / (1.0f + __expf(-v[t]));
    } else if (t < 2 * NN) {
        const int i = t - NN;
        ws[32 + i] = 2.0f / (1.0f + __expf(-b[i]));
    } else if (t < 3 * NN) {
        const int i = t - 2 * NN;
        ws[64 + i] = 10.0f / (1.0f + __expf(-c[i]));
    }
}

// 2 batch elements per wave: lanes 0-31 -> element 2p, lanes 32-63 -> element 2p+1.
// Lane owns oscillator i = tid&31. A/B rows live in VGPRs; u,v roundtrip through a
// per-half-wave LDS slice and are read back with broadcast ds_read_b128.
__global__ __launch_bounds__(256, 4)
void hopf_kernel(const float* __restrict__ states,
                 const float* __restrict__ ws,
                 float* __restrict__ out,
                 const int npairs) {
    // 8 waves/block * 2 slices/wave; 34 = 32 + pad so the two half-wave slices
    // land on different banks (272 B stride), slices 16B-aligned for b128 reads.
    __shared__ __align__(16) float2 uv[16][34];

    const int tid   = threadIdx.x;
    const int i     = tid & 31;          // oscillator index
    const int slice = tid >> 5;          // 0..15: (wave-in-block)*2 + half
    const int half  = slice & 1;

    const float va2pi = ws[i];
    const float ba    = ws[32 + i];
    const float ca    = ws[64 + i];

    // A/B row of this lane's oscillator -> registers (one-time, L2-served).
    float Ar[NN], Br[NN];
    {
        const float4* Ag = (const float4*)(ws + 128  + i * NN);
        const float4* Bg = (const float4*)(ws + 1152 + i * NN);
#pragma unroll
        for (int q = 0; q < 8; ++q) {
            const float4 a4 = Ag[q];
            const float4 b4 = Bg[q];
            Ar[4*q+0] = a4.x; Ar[4*q+1] = a4.y; Ar[4*q+2] = a4.z; Ar[4*q+3] = a4.w;
            Br[4*q+0] = b4.x; Br[4*q+1] = b4.y; Br[4*q+2] = b4.z; Br[4*q+3] = b4.w;
        }
    }

    const int gwave  = (blockIdx.x * blockDim.x + tid) >> 6;
    const int nwaves = (gridDim.x * blockDim.x) >> 6;

    for (int p = gwave; p < npairs; p += nwaves) {
        const int e    = 2 * p + half;
        const int base = e * STRIDE3 + i;

        const float psi = states[base];
        const float r   = states[base + 32];
        const float rd  = states[base + 64];

        float s, c;
        __sincosf(psi, &s, &c);

        const float rdd = ca * (ca * 0.25f * (ba - r) - rd);

        // publish u,v for this element; wave-synchronous (in-order DS pipe,
        // both halves of the wave write disjoint slices)
        uv[slice][i] = make_float2(r * s, r * c);
        __builtin_amdgcn_wave_barrier();
        __asm__ volatile("" ::: "memory");

        float P = 0.f, Q = 0.f;
        const float4* uvq = (const float4*)(&uv[slice][0]);
#pragma unroll
        for (int jj = 0; jj < 16; ++jj) {
            const float4 q4 = uvq[jj];        // {u_j, v_j, u_j+1, v_j+1}, broadcast
            const int j0 = 2 * jj, j1 = 2 * jj + 1;
            P = fmaf(Ar[j0],  q4.x, P);
            P = fmaf(-Br[j0], q4.y, P);
            Q = fmaf(Ar[j0],  q4.y, Q);
            Q = fmaf(Br[j0],  q4.x, Q);
            P = fmaf(Ar[j1],  q4.z, P);
            P = fmaf(-Br[j1], q4.w, P);
            Q = fmaf(Ar[j1],  q4.w, Q);
            Q = fmaf(Br[j1],  q4.z, Q);
        }
        __builtin_amdgcn_wave_barrier();
        __asm__ volatile("" ::: "memory");

        out[base]      = va2pi + c * P - s * Q;  // psi_dot
        out[base + 32] = rd;                     // r_d passthrough
        out[base + 64] = rdd;                    // r_d_dot
    }
}

extern "C" void kernel_launch(void* const* d_in, const int* in_sizes, int n_in,
                              void* d_out, int out_size, void* d_ws, size_t ws_size,
                              hipStream_t stream) {
    const float* states = (const float*)d_in[0];
    const float* v      = (const float*)d_in[1];
    const float* b      = (const float*)d_in[2];
    const float* c      = (const float*)d_in[3];
    const float* w      = (const float*)d_in[4];
    const float* phi    = (const float*)d_in[5];
    float* out = (float*)d_out;
    float* ws  = (float*)d_ws;

    const int B = in_sizes[0] / STRIDE3;
    const int npairs = B / 2;

    precompute_kernel<<<1, 1024, 0, stream>>>(v, b, c, w, phi, ws);

    // 1024 blocks * 256 thr = 4096 waves = 4 waves/SIMD resident; 8 pairs/wave.
    hopf_kernel<<<1024, 256, 0, stream>>>(states, ws, out, npairs);
}

// Round 2
// 91.314 us; speedup vs baseline: 1.0541x; 1.0541x over previous
//
#include <hip/hip_runtime.h>
#include <math.h>

#define NN 32
#define STRIDE3 96            // 3*NN floats per batch element
#define PI_F 3.14159265358979323846f

// Single fused kernel.
// Phase 0 (per block, one-time): compute activations + zero-diag A/B matrices
//   A_ij = w_a*cos(phi_a), B_ij = w_a*sin(phi_a) into padded LDS, pull rows
//   into VGPRs (conflict-free b32 reads, stride 33).
// Main loop: 2 batch elements per wave (lanes 0-31 / 32-63), lane = oscillator.
//   coupling_i = c_i*(A u - B v)_i - s_i*(A v + B u)_i with u=r sin(psi),
//   v=r cos(psi): a 32x32 real matvec pair, exchanged through a per-half-wave
//   LDS slice read back as broadcast ds_read_b128.
//   Next iteration's states are prefetched BEFORE the LDS-exchange memory
//   clobbers so global-load latency pipelines across grid-stride iterations.
__global__ __launch_bounds__(256, 4)
void hopf_kernel(const float* __restrict__ states,
                 const float* __restrict__ v,
                 const float* __restrict__ b,
                 const float* __restrict__ c,
                 const float* __restrict__ w,
                 const float* __restrict__ phi,
                 float* __restrict__ out,
                 const int npairs) {
    __shared__ float As[NN][33];   // +1 pad: row reads conflict-free
    __shared__ float Bs[NN][33];
    // 4 waves/block * 2 slices/wave; 34 = 32 + pad (272 B slice stride, 16B-aligned)
    __shared__ __align__(16) float2 uv[8][34];

    const int tid   = threadIdx.x;
    const int i     = tid & 31;          // oscillator index
    const int slice = tid >> 5;          // 0..7: (wave-in-block)*2 + half
    const int half  = slice & 1;

    // ---- Phase 0: A/B matrices (redundant per block, one-time) ----
    for (int t = tid; t < NN * NN; t += 256) {
        // _zero_diag: flat t -> 0 if t%33==0, else param[t/33][t%33-1]
        float A = 0.f, Bv = 0.f;
        const int rem = t % 33;
        if (rem != 0) {
            const int a = t / 33;
            const int col = rem - 1;
            const float wa = 1.0f / (1.0f + __expf(-w[a * NN + col]));          // W_MAX=1
            const float pa = (2.0f * PI_F) / (1.0f + __expf(-phi[a * NN + col])); // PHI_MAX=2pi
            float sp, cp;
            __sincosf(pa, &sp, &cp);
            A = wa * cp;
            Bv = wa * sp;
        }
        As[t >> 5][t & 31] = A;
        Bs[t >> 5][t & 31] = Bv;
    }
    __syncthreads();

    // per-lane activations (3 coalesced dword loads, L1-resident)
    const float va2pi = 2.0f * PI_F * 5.0f / (1.0f + __expf(-v[i]));
    const float ba    = 2.0f  / (1.0f + __expf(-b[i]));
    const float ca    = 10.0f / (1.0f + __expf(-c[i]));

    // rows -> registers (one-time, conflict-free stride-33 b32 reads)
    float Ar[NN], Br[NN];
#pragma unroll
    for (int j = 0; j < NN; ++j) {
        Ar[j] = As[i][j];
        Br[j] = Bs[i][j];
    }

    const int gwave  = (blockIdx.x * blockDim.x + tid) >> 6;
    const int nwaves = (gridDim.x * blockDim.x) >> 6;

    // ---- main loop, prefetch distance 1 ----
    int p = gwave;
    float c_psi = 0.f, c_r = 0.f, c_rd = 0.f;
    if (p < npairs) {
        const int base = (2 * p + half) * STRIDE3 + i;
        c_psi = states[base];
        c_r   = states[base + 32];
        c_rd  = states[base + 64];
    }

    for (; p < npairs; p += nwaves) {
        // prefetch next iteration BEFORE any memory clobber in this one
        const int pn = p + nwaves;
        float n_psi = 0.f, n_r = 0.f, n_rd = 0.f;
        if (pn < npairs) {
            const int nb = (2 * pn + half) * STRIDE3 + i;
            n_psi = states[nb];
            n_r   = states[nb + 32];
            n_rd  = states[nb + 64];
        }

        float s, cc;
        __sincosf(c_psi, &s, &cc);
        const float rdd = ca * (ca * 0.25f * (ba - c_r) - c_rd);

        // publish u,v (wave-synchronous: in-order DS pipe, disjoint slices)
        uv[slice][i] = make_float2(c_r * s, c_r * cc);
        __builtin_amdgcn_wave_barrier();
        __asm__ volatile("" ::: "memory");

        float P = 0.f, Q = 0.f;
        const float4* uvq = (const float4*)(&uv[slice][0]);
#pragma unroll
        for (int jj = 0; jj < 16; ++jj) {
            const float4 q4 = uvq[jj];        // {u_j, v_j, u_j+1, v_j+1}, broadcast
            const int j0 = 2 * jj, j1 = 2 * jj + 1;
            P = fmaf(Ar[j0],  q4.x, P);
            P = fmaf(-Br[j0], q4.y, P);
            Q = fmaf(Ar[j0],  q4.y, Q);
            Q = fmaf(Br[j0],  q4.x, Q);
            P = fmaf(Ar[j1],  q4.z, P);
            P = fmaf(-Br[j1], q4.w, P);
            Q = fmaf(Ar[j1],  q4.w, Q);
            Q = fmaf(Br[j1],  q4.z, Q);
        }
        __builtin_amdgcn_wave_barrier();
        __asm__ volatile("" ::: "memory");

        const int ob = (2 * p + half) * STRIDE3 + i;
        out[ob]      = va2pi + cc * P - s * Q;  // psi_dot
        out[ob + 32] = c_rd;                    // r_d passthrough
        out[ob + 64] = rdd;                     // r_d_dot

        c_psi = n_psi; c_r = n_r; c_rd = n_rd;
    }
}

extern "C" void kernel_launch(void* const* d_in, const int* in_sizes, int n_in,
                              void* d_out, int out_size, void* d_ws, size_t ws_size,
                              hipStream_t stream) {
    const float* states = (const float*)d_in[0];
    const float* v      = (const float*)d_in[1];
    const float* b      = (const float*)d_in[2];
    const float* c      = (const float*)d_in[3];
    const float* w      = (const float*)d_in[4];
    const float* phi    = (const float*)d_in[5];
    float* out = (float*)d_out;

    const int B = in_sizes[0] / STRIDE3;
    const int npairs = B / 2;

    // 1024 blocks * 4 waves = 4096 waves = 4 waves/SIMD resident; 8 pairs/wave.
    hopf_kernel<<<1024, 256, 0, stream>>>(states, v, b, c, w, phi, out, npairs);
}